// Round 9
// baseline (416.460 us; speedup 1.0000x reference)
//
#include <hip/hip_runtime.h>
#include <stdint.h>

#define DEV static __device__ __forceinline__

typedef __attribute__((ext_vector_type(8))) short s16x8;
typedef __attribute__((ext_vector_type(4))) short s16x4;
typedef __attribute__((ext_vector_type(4))) float f32x4;

constexpr int BB = 2, LL = 2048, DD = 2048, NH = 16, NKV = 4, HD = 128;
constexpr int Mrows = BB * LL;            // 4096
constexpr int NQKV = DD + 2 * NKV * HD;   // 3072

DEV ushort f2bf(float f){
  union { float f; uint32_t u; } v; v.f = f;
  uint32_t u = v.u;
  u += 0x7fffu + ((u >> 16) & 1u);
  return (ushort)(u >> 16);
}
DEV float bf2f(ushort h){
  union { uint32_t u; float f; } v; v.u = ((uint32_t)h) << 16;
  return v.f;
}

DEV f32x4 mfma32(s16x8 a, s16x8 b, f32x4 c){
  return __builtin_amdgcn_mfma_f32_16x16x32_bf16(a, b, c, 0, 0, 0);
}
DEV f32x4 mfma16(s16x4 a, s16x4 b, f32x4 c){
#if __has_builtin(__builtin_amdgcn_mfma_f32_16x16x16bf16_1k)
  return __builtin_amdgcn_mfma_f32_16x16x16bf16_1k(a, b, c, 0, 0, 0);
#else
  asm volatile("v_mfma_f32_16x16x16_bf16 %0, %1, %2, %0" : "+v"(c) : "v"(a), "v"(b));
  return c;
#endif
}

DEV float vmax4(f32x4 v){ return fmaxf(fmaxf(v[0], v[1]), fmaxf(v[2], v[3])); }
DEV float vsum4(f32x4 v){ return (v[0] + v[1]) + (v[2] + v[3]); }

// ---------------- fused fp32 -> bf16 conversion for all 5 inputs ----------------
__global__ void cvt_all_kernel(const float* __restrict__ x, const float* __restrict__ wq,
                               const float* __restrict__ wk, const float* __restrict__ wv,
                               const float* __restrict__ wo,
                               ushort* __restrict__ xb, ushort* __restrict__ wqkv,
                               ushort* __restrict__ wob){
  constexpr int C0 = Mrows * DD / 4;                 // x
  constexpr int C1 = C0 + DD * DD / 4;               // wq
  constexpr int C2 = C1 + NKV * HD * DD / 4;         // wk
  constexpr int C3 = C2 + NKV * HD * DD / 4;         // wv
  constexpr int C4 = C3 + DD * DD / 4;               // wo
  int stride = gridDim.x * blockDim.x;
  for (int i = blockIdx.x * blockDim.x + threadIdx.x; i < C4; i += stride){
    const float* src; ushort* dst; int j;
    if (i < C0){ src = x;  dst = xb;                              j = i; }
    else if (i < C1){ src = wq; dst = wqkv;                       j = i - C0; }
    else if (i < C2){ src = wk; dst = wqkv + (size_t)DD * DD;     j = i - C1; }
    else if (i < C3){ src = wv; dst = wqkv + (size_t)(DD + NKV*HD) * DD; j = i - C2; }
    else { src = wo; dst = wob;                                   j = i - C3; }
    float4 v = reinterpret_cast<const float4*>(src)[j];
    ushort4 o = make_ushort4(f2bf(v.x), f2bf(v.y), f2bf(v.z), f2bf(v.w));
    reinterpret_cast<ushort4*>(dst)[j] = o;
  }
}

// ---------------- RoPE tables: cos/sin [L][64] fp32 ----------------
__global__ void rope_table_kernel(float* __restrict__ cosT, float* __restrict__ sinT){
  int i = blockIdx.x * blockDim.x + threadIdx.x;
  if (i >= LL * 64) return;
  int l = i >> 6, f = i & 63;
  float inv = __expf(-logf(10000.f) * (float)f / 64.f);
  float ang = (float)l * inv;
  float s, c;
  sincosf(ang, &s, &c);
  cosT[i] = c; sinT[i] = s;
}

// ---------------- fused RoPE apply in place on Q and K ----------------
__global__ void rope_qk_kernel(ushort* __restrict__ q, ushort* __restrict__ k,
                               const float* __restrict__ cosT, const float* __restrict__ sinT){
  constexpr int TQ = BB * NH * LL * 16;
  constexpr int TK = BB * NKV * LL * 16;
  int idx = blockIdx.x * blockDim.x + threadIdx.x;
  if (idx >= TQ + TK) return;
  ushort* t; float scale; int id;
  if (idx < TQ){ t = q; id = idx; scale = 0.08838834764831845f; }  // 1/sqrt(128)
  else { t = k; id = idx - TQ; scale = 1.0f; }
  int c = id & 15;
  int l = (id >> 4) & (LL - 1);
  s16x8 v = *reinterpret_cast<const s16x8*>(t + (size_t)id * 8);
  int fb = (l << 6) + c * 4;
  s16x8 o;
  #pragma unroll
  for (int j = 0; j < 4; ++j){
    float x1 = bf2f((ushort)v[2*j]);
    float x2 = bf2f((ushort)v[2*j+1]);
    float co = cosT[fb + j], si = sinT[fb + j];
    o[2*j]   = (short)f2bf((x1 * co - x2 * si) * scale);
    o[2*j+1] = (short)f2bf((x1 * si + x2 * co) * scale);
  }
  *reinterpret_cast<s16x8*>(t + (size_t)id * 8) = o;
}

// ---------------- async global->LDS helper ----------------
DEV void g2l16(const void* g, void* l){
  __builtin_amdgcn_global_load_lds((__attribute__((address_space(1))) void*)(void*)g,
                                   (__attribute__((address_space(3))) void*)l, 16, 0, 0);
}

// ============ 256x256 8-phase GEMM (T3+T4+T5+T2), BK=64 as two K=32 half-slices =====
// C = A(4096 x K) * W(N x K)^T.  8 waves (2M x 4N), per-wave C = 128x64.
// LDS (dynamic 128KB): A[2 buf][2 kh][256 rows][32 k], B same. Rows = 64B = 4 chunks.
// T2 swizzle: LDS(row, chunk) holds logical (row, chunk ^ ((row>>1)&3)) — applied as
// pre-swizzled GLOBAL source (gload_lds dest linear, rule #21) + XOR on frag reads.
// Ring schedule (verified r7/r8): phases p1..p8 stage
//   p1:H(t+1,A,kh1) p2:H(t+1,B,kh1) p3:H(t+2,A,kh0) p4:H(t+2,B,kh0)+vmcnt(4)
//   p5:H(t+2,A,kh1) p6:H(t+2,B,kh1) p7:H(t+3,A,kh0) p8:H(t+3,B,kh0)+vmcnt(4)
// ntiles = K-span/64 per block; blockIdx.y selects a K-split (MODE 0 uses atomicAdd).
// MODE 0: fp32 out [row][2048] via atomicAdd (out pre-zeroed).  MODE 1: QKV scatter.
#define GPHASE(DB, KK, MH, SDB, SKH, SB, ST, VM) { \
    const ushort* As_ = Asm + ((DB)*2 + (KK)) * 8192 + wm * 128 * 32; \
    const ushort* Bs_ = Bsm + ((DB)*2 + (KK)) * 8192 + wn * 64 * 32; \
    s16x8 af_[4], bf_[4]; \
    _Pragma("unroll") \
    for (int i_ = 0; i_ < 4; ++i_) \
      af_[i_] = *(const s16x8*)&As_[(((MH)*4 + i_) * 16 + lr) * 32 + swz]; \
    _Pragma("unroll") \
    for (int n_ = 0; n_ < 4; ++n_) \
      bf_[n_] = *(const s16x8*)&Bs_[(n_ * 16 + lr) * 32 + swz]; \
    STG(SDB, SKH, SB, ST); \
    if (VM) asm volatile("s_waitcnt vmcnt(4)" ::: "memory"); \
    __builtin_amdgcn_s_barrier(); \
    __builtin_amdgcn_s_setprio(1); \
    _Pragma("unroll") \
    for (int i_ = 0; i_ < 4; ++i_) \
      _Pragma("unroll") \
      for (int n_ = 0; n_ < 4; ++n_) \
        acc[(MH)*4 + i_][n_] = mfma32(af_[i_], bf_[n_], acc[(MH)*4 + i_][n_]); \
    __builtin_amdgcn_s_setprio(0); \
    __builtin_amdgcn_s_barrier(); \
  }

template<int MODE>
__global__ __launch_bounds__(512, 2) void gemm256_kernel(const ushort* __restrict__ A,
    const ushort* __restrict__ W, float* __restrict__ fout, ushort* __restrict__ qo,
    ushort* __restrict__ ko, ushort* __restrict__ vo, int ntiles)
{
  extern __shared__ ushort smem[];          // 128 KB
  ushort* Asm = smem;                        // [2][2][256][32] = 32768 elems
  ushort* Bsm = smem + 32768;
  const int tid = threadIdx.x;
  const int w = tid >> 6, lane = tid & 63;
  const int lr = lane & 15, lg = lane >> 4;
  const int wm = w >> 2, wn = w & 3;
  // read-side swizzle: chunk' = lg ^ ((row>>1)&3); row bases are == 0 mod 4 rows.
  const int swz = (lg ^ ((lr >> 1) & 3)) * 8;
  const int cpx = (int)gridDim.x >> 3;       // blocks per XCD (grid.x % 8 == 0)
  const int id = (int)blockIdx.x;
  const int nid = (id & 7) * cpx + (id >> 3);
  const int bx = nid >> 4, by = nid & 15;    // W-panel-major within an XCD chunk
  const int brow = by * 256, bcol = bx * 256;
  const int kbase = (int)blockIdx.y * ntiles * 64;   // K-split offset

  // staging: dest (row = w*32 + lane>>2, chunk = lane&3); source chunk pre-swizzled
  // by ((row>>1)&3) = ((lane>>3)&3).
  const int schunk = ((lane & 3) ^ ((lane >> 3) & 3)) * 8;
  const ushort* gA = A + (size_t)(brow + w*32 + (lane >> 2)) * 2048 + kbase + schunk;
  const ushort* gW = W + (size_t)(bcol + w*32 + (lane >> 2)) * 2048 + kbase + schunk;
  const int ldsOff = w * 1024 + lane * 8;    // linear: base + lane*16B

  f32x4 acc[8][4] = {};

  auto STG = [&](int db, int kh, int isB, int tile){
    const ushort* g = (isB ? gW : gA) + tile * 64 + kh * 32;
    ushort* l = (isB ? Bsm : Asm) + (db*2 + kh) * 8192 + ldsOff;
    g2l16(g, l);
    g2l16(g + 16 * 2048, l + 512);
  };

  // prologue: tile0 complete + tile1 kh0 in flight
  STG(0,0,0,0); STG(0,0,1,0); STG(0,1,0,0); STG(0,1,1,0); STG(1,0,0,1); STG(1,0,1,1);
  asm volatile("s_waitcnt vmcnt(4)" ::: "memory");
  __builtin_amdgcn_s_barrier();

  const int tmax = ntiles - 1;
  for (int it = 0; it < (ntiles >> 1); ++it){
    const int t  = 2 * it;
    const int t2 = (t + 2 < tmax) ? t + 2 : tmax;
    const int t3 = (t + 3 < tmax) ? t + 3 : tmax;
    GPHASE(0,0,0, 1,1,0, t+1, 0);
    GPHASE(0,0,1, 1,1,1, t+1, 0);
    GPHASE(0,1,0, 0,0,0, t2,  0);
    GPHASE(0,1,1, 0,0,1, t2,  1);
    GPHASE(1,0,0, 0,1,0, t2,  0);
    GPHASE(1,0,1, 0,1,1, t2,  0);
    GPHASE(1,1,0, 1,0,0, t3,  0);
    GPHASE(1,1,1, 1,0,1, t3,  1);
  }
  // drain remaining prefetches before endpgm (protect successor blocks' LDS).
  asm volatile("s_waitcnt vmcnt(0)" ::: "memory");

  #pragma unroll
  for (int mf = 0; mf < 8; ++mf)
    #pragma unroll
    for (int nf = 0; nf < 4; ++nf)
      #pragma unroll
      for (int r = 0; r < 4; ++r){
        int row = brow + wm*128 + mf*16 + lg*4 + r;
        int col = bcol + wn*64 + nf*16 + lr;
        float v = acc[mf][nf][r];
        if (MODE == 0){
          atomicAdd(&fout[(size_t)row * DD + col], v);
        } else {
          int b = row >> 11, l = row & (LL - 1);
          ushort bv = f2bf(v);
          if (col < DD){
            qo[(((size_t)(b * NH + (col >> 7))) * LL + l) * HD + (col & 127)] = bv;
          } else if (col < DD + NKV * HD){
            int c = col - DD;
            ko[(((size_t)(b * NKV + (c >> 7))) * LL + l) * HD + (c & 127)] = bv;
          } else {
            int c = col - DD - NKV * HD;
            vo[(((size_t)(b * NKV + (c >> 7))) * HD + (c & 127)) * LL + l] = bv;
          }
        }
      }
}

// ---------------- flash attention, diagonal-paired for causal balance -------------
// Each block owns q-blocks {p, 31-p}: 33 tile-steps, nt = 32-p staging iterations.
// CU-level balance: a CU's two blocks (ids c, c+256 -> nids n, n+32) differ in nid
// bit5, so pair is derived from bit5: pair sums per CU = 49 staging iters (uniform).
template<int NQ>
DEV void tile_step(const ushort* __restrict__ Ks, const ushort* __restrict__ Vs,
                   const s16x8 (*qf)[4], f32x4 (*of)[8], float* mrun, float* lrun,
                   const int* qrow, int jb, int lr, int lg)
{
  f32x4 s[4][NQ];
  #pragma unroll
  for (int kt = 0; kt < 4; ++kt)
    #pragma unroll
    for (int q = 0; q < NQ; ++q) s[kt][q] = (f32x4){0.f, 0.f, 0.f, 0.f};

  __builtin_amdgcn_s_setprio(1);
  #pragma unroll
  for (int kk = 0; kk < 4; ++kk)
    #pragma unroll
    for (int kt = 0; kt < 4; ++kt){
      s16x8 kf = *reinterpret_cast<const s16x8*>(
          &Ks[((kt*16 + lr) << 7) + (((kk*4 + lg) ^ (lr & 7)) << 3)]);
      #pragma unroll
      for (int q = 0; q < NQ; ++q)
        s[kt][q] = mfma32(kf, qf[q][kk], s[kt][q]);
    }
  __builtin_amdgcn_s_setprio(0);

  #pragma unroll
  for (int q = 0; q < NQ; ++q)
    if (jb + 63 > qrow[q]){
      int qg = qrow[q] + lr;
      #pragma unroll
      for (int kt = 0; kt < 4; ++kt){
        int kvg = jb + kt*16 + lg*4;
        #pragma unroll
        for (int r = 0; r < 4; ++r)
          if (kvg + r > qg) s[kt][q][r] = -1e30f;
      }
    }

  float mx[NQ];
  #pragma unroll
  for (int q = 0; q < NQ; ++q){
    mx[q] = fmaxf(fmaxf(vmax4(s[0][q]), vmax4(s[1][q])),
                  fmaxf(vmax4(s[2][q]), vmax4(s[3][q])));
    mx[q] = fmaxf(mx[q], __shfl_xor(mx[q], 16, 64));
    mx[q] = fmaxf(mx[q], __shfl_xor(mx[q], 32, 64));
  }
  int small = 1;
  #pragma unroll
  for (int q = 0; q < NQ; ++q) small &= (mx[q] <= mrun[q] + 8.f);
  if (!__all(small)){
    #pragma unroll
    for (int q = 0; q < NQ; ++q){
      float mn = fmaxf(mrun[q], mx[q]);
      float fac = __expf(mrun[q] - mn);
      mrun[q] = mn;
      lrun[q] *= fac;
      #pragma unroll
      for (int f = 0; f < 8; ++f) of[q][f] *= fac;
    }
  }
  float ps[NQ];
  #pragma unroll
  for (int q = 0; q < NQ; ++q) ps[q] = 0.f;
  #pragma unroll
  for (int kt = 0; kt < 4; ++kt)
    #pragma unroll
    for (int q = 0; q < NQ; ++q){
      #pragma unroll
      for (int r = 0; r < 4; ++r)
        s[kt][q][r] = __expf(s[kt][q][r] - mrun[q]);
      ps[q] += vsum4(s[kt][q]);
    }
  #pragma unroll
  for (int q = 0; q < NQ; ++q){
    ps[q] += __shfl_xor(ps[q], 16, 64);
    ps[q] += __shfl_xor(ps[q], 32, 64);
    lrun[q] += ps[q];
  }
  s16x4 pb[4][NQ];
  #pragma unroll
  for (int kt = 0; kt < 4; ++kt)
    #pragma unroll
    for (int q = 0; q < NQ; ++q){
      s16x4 pv;
      #pragma unroll
      for (int r = 0; r < 4; ++r) pv[r] = (short)f2bf(s[kt][q][r]);
      pb[kt][q] = pv;
    }
  __builtin_amdgcn_s_setprio(1);
  #pragma unroll
  for (int f = 0; f < 8; ++f)
    #pragma unroll
    for (int kt = 0; kt < 4; ++kt){
      s16x4 va = *reinterpret_cast<const s16x4*>(
          &Vs[((f*16 + lr) << 6) + (((2*kt + (lg >> 1)) ^ (lr & 7)) << 3) + ((lg & 1) << 2)]);
      #pragma unroll
      for (int q = 0; q < NQ; ++q)
        of[q][f] = mfma16(va, pb[kt][q], of[q][f]);
    }
  __builtin_amdgcn_s_setprio(0);
}

__global__ __launch_bounds__(256) void attn_kernel(const ushort* __restrict__ Q,
    const ushort* __restrict__ Kg, const ushort* __restrict__ VTg, ushort* __restrict__ O)
{
  __shared__ ushort Ksm[2][64 * 128];
  __shared__ ushort Vsm[2][128 * 64];
  const int tid = threadIdx.x;
  const int w = tid >> 6, lane = tid & 63;
  const int lr = lane & 15, lg = lane >> 4;
  // XCD-chunked: nid in [x*64, x*64+63] for XCD x -> one (b,kvh) KV pair per XCD.
  const int id = blockIdx.x;
  const int nid = (id & 7) * 64 + (id >> 3);
  const int q4 = nid & 15;
  const int b4 = (nid >> 4) & 1;
  const int hi = (nid >> 5) & 1;
  const int bh = (nid >> 6) * 4 + b4 * 2 + hi;      // 0..31 (b, h)
  const int pair = hi ? (15 - q4) : q4;             // CU-balanced complement
  const int b = bh >> 4, h = bh & 15, kvh = h >> 2;
  const size_t qoff = (size_t)bh * LL * HD;
  const size_t koff = (size_t)(b * NKV + kvh) * LL * HD;
  const size_t voff = (size_t)(b * NKV + kvh) * HD * LL;
  const int qrow[2] = { pair*64 + w*16, (31 - pair)*64 + w*16 };
  const int nt  = 32 - pair;
  const int ntA = pair + 1;

  s16x8 qf[2][4];
  #pragma unroll
  for (int qt = 0; qt < 2; ++qt)
    #pragma unroll
    for (int kk = 0; kk < 4; ++kk)
      qf[qt][kk] = *reinterpret_cast<const s16x8*>(
          &Q[qoff + (size_t)(qrow[qt] + lr) * HD + kk*32 + lg*8]);

  f32x4 of[2][8] = {};
  float mrun[2] = {-1e30f, -1e30f}, lrun[2] = {0.f, 0.f};

  auto STAGE = [&](int buf, int jb){
    #pragma unroll
    for (int it = 0; it < 4; ++it){
      int chunk = it * 256 + tid;
      int r = chunk >> 4, c = chunk & 15;
      g2l16(Kg + koff + (size_t)(jb + r) * HD + ((c ^ (r & 7)) << 3), &Ksm[buf][chunk << 3]);
    }
    #pragma unroll
    for (int it = 0; it < 4; ++it){
      int chunk = it * 256 + tid;
      int r = chunk >> 3, c = chunk & 7;
      g2l16(VTg + voff + (size_t)r * LL + jb + ((c ^ (r & 7)) << 3), &Vsm[buf][chunk << 3]);
    }
  };
  STAGE(0, 0);

  for (int t = 0; t < nt; ++t){
    const int jb = t << 6, cur = t & 1;
    __syncthreads();
    if (t + 1 < nt) STAGE(cur ^ 1, (t + 1) << 6);
    if (t < ntA)
      tile_step<2>(Ksm[cur], Vsm[cur], qf, of, mrun, lrun, qrow, jb, lr, lg);
    else
      tile_step<1>(Ksm[cur], Vsm[cur], qf + 1, of + 1, mrun + 1, lrun + 1, qrow + 1, jb, lr, lg);
  }

  #pragma unroll
  for (int qt = 0; qt < 2; ++qt){
    float inv = 1.0f / lrun[qt];
    #pragma unroll
    for (int f = 0; f < 8; ++f)
      #pragma unroll
      for (int r = 0; r < 4; ++r){
        int row = qrow[qt] + lr;
        int col = h * HD + f*16 + lg*4 + r;
        O[((size_t)b * LL + row) * DD + col] = f2bf(of[qt][f][r] * inv);
      }
  }
}

// ---------------- launcher ----------------
extern "C" void kernel_launch(void* const* d_in, const int* in_sizes, int n_in,
                              void* d_out, int out_size, void* d_ws, size_t ws_size,
                              hipStream_t stream)
{
  const float* x  = (const float*)d_in[0];
  const float* wq = (const float*)d_in[1];
  const float* wk = (const float*)d_in[2];
  const float* wv = (const float*)d_in[3];
  const float* wo = (const float*)d_in[4];
  float* out = (float*)d_out;

  char* p = (char*)d_ws;
  auto alloc = [&](size_t bytes) -> void* {
    void* r = (void*)p; p += (bytes + 255) & ~(size_t)255; return r;
  };
  ushort* xb    = (ushort*)alloc((size_t)Mrows * DD * 2);
  ushort* wqkvb = (ushort*)alloc((size_t)NQKV * DD * 2);
  ushort* wob   = (ushort*)alloc((size_t)DD * DD * 2);
  ushort* qws   = (ushort*)alloc((size_t)BB * NH * LL * HD * 2);
  ushort* kws   = (ushort*)alloc((size_t)BB * NKV * LL * HD * 2);
  ushort* vws   = (ushort*)alloc((size_t)BB * NKV * LL * HD * 2);  // V^T layout
  ushort* aows  = (ushort*)alloc((size_t)Mrows * DD * 2);
  float*  cosT  = (float*)alloc((size_t)LL * 64 * 4);
  float*  sinT  = (float*)alloc((size_t)LL * 64 * 4);

  hipFuncSetAttribute(reinterpret_cast<const void*>(gemm256_kernel<1>),
                      hipFuncAttributeMaxDynamicSharedMemorySize, 131072);
  hipFuncSetAttribute(reinterpret_cast<const void*>(gemm256_kernel<0>),
                      hipFuncAttributeMaxDynamicSharedMemorySize, 131072);

  // zero-init output for the split-K atomic epilogue
  hipMemsetAsync(out, 0, (size_t)Mrows * DD * sizeof(float), stream);

  hipLaunchKernelGGL(cvt_all_kernel, dim3(2048), dim3(256), 0, stream,
                     x, wq, wk, wv, wo, xb, wqkvb, wob);
  hipLaunchKernelGGL(rope_table_kernel, dim3((LL*64)/256), dim3(256), 0, stream, cosT, sinT);

  // fused QKV projection, 256^2 8-phase (V written transposed): 192 blocks, K=2048
  hipLaunchKernelGGL(gemm256_kernel<1>, dim3(192), dim3(512), 131072, stream,
                     xb, wqkvb, (float*)nullptr, qws, kws, vws, 32);

  // fused RoPE on Q (pre-scaled) and K
  {
    constexpr int tot = BB*NH*LL*16 + BB*NKV*LL*16;
    hipLaunchKernelGGL(rope_qk_kernel, dim3(tot/256), dim3(256), 0, stream,
                       qws, kws, cosT, sinT);
  }

  // attention: diagonal-paired blocks, CU-balanced pair assignment
  hipLaunchKernelGGL(attn_kernel, dim3(512), dim3(256), 0, stream,
                     qws, kws, vws, aows);

  // output projection, split-K=2 (128 x 2 = 256 blocks), atomic fp32 epilogue
  hipLaunchKernelGGL(gemm256_kernel<0>, dim3(128, 2), dim3(512), 131072, stream,
                     aows, wob, out, (ushort*)nullptr, (ushort*)nullptr, (ushort*)nullptr, 16);
}